// Round 5
// baseline (279.632 us; speedup 1.0000x reference)
//
#include <hip/hip_runtime.h>

#define BLOCK  256
#define GRID   2048
#define S4     512    // float4 per array per stage (8 KiB)
#define STAGES 8      // per-block: S4*STAGES = 4096 float4/array; GRID*4096*4 = 2^25 elems

typedef float vfloat4 __attribute__((ext_vector_type(4)));

// Async DMA global -> LDS, 16 B per lane. LDS dest is WAVE-UNIFORM base;
// HW scatters lane i's 16 B to base + i*16. Global ptr is per-lane.
__device__ __forceinline__ void async_cp16(const vfloat4* g, vfloat4* lds_base) {
    __builtin_amdgcn_global_load_lds(
        (const __attribute__((address_space(1))) unsigned int*)g,
        (__attribute__((address_space(3))) unsigned int*)lds_base,
        16, 0, 0);
}

__device__ __forceinline__ void kl_acc(float p, float q, float& acc) {
    // log2-space: acc += p*(log2 p - log2 q) + (1-p)*(log2(1-p) - log2(1-q))
    float omp = 1.0f - p;
    float omq = 1.0f - q;
    float d1  = __log2f(p)   - __log2f(q);
    float d2  = __log2f(omp) - __log2f(omq);
    acc = fmaf(p,   d1, acc);
    acc = fmaf(omp, d2, acc);
}

__device__ __forceinline__ void kl_acc4(vfloat4 pv, vfloat4 qv,
                                        float& a0, float& a1, float& a2, float& a3) {
    kl_acc(pv.x, qv.x, a0);
    kl_acc(pv.y, qv.y, a1);
    kl_acc(pv.z, qv.z, a2);
    kl_acc(pv.w, qv.w, a3);
}

__device__ __forceinline__ void block_reduce_and_atomic(float acc, float* out) {
    const float LN2 = 0.69314718055994530942f;
    #pragma unroll
    for (int off = 32; off > 0; off >>= 1)
        acc += __shfl_down(acc, off, 64);

    __shared__ float wave_sums[BLOCK / 64];
    const int lane = threadIdx.x & 63;
    const int wave = threadIdx.x >> 6;
    if (lane == 0) wave_sums[wave] = acc;
    __syncthreads();

    if (threadIdx.x == 0) {
        float s = 0.0f;
        #pragma unroll
        for (int w = 0; w < BLOCK / 64; ++w) s += wave_sums[w];
        atomicAdd(out, s * LN2);
    }
}

// LDS-DMA streamer: dodge the global_load->VGPR return clamp (4 B/cyc/CU
// observed R0-R4) via the global_load_lds path (m97: >21 B/cyc/CU).
__global__ __launch_bounds__(BLOCK, 4) void kl_div_lds(
        const vfloat4* __restrict__ p4,
        const vfloat4* __restrict__ q4,
        float* __restrict__ out) {
    __shared__ vfloat4 sp[2][S4];
    __shared__ vfloat4 sq[2][S4];

    const int t    = threadIdx.x;
    const int w    = t >> 6;          // wave 0..3
    const int lane = t & 63;
    const size_t base = (size_t)blockIdx.x * (S4 * STAGES);  // float4 index

    // Wave w stages its 128-float4 quarter of each array: 2 DMA instrs/array.
    auto stage = [&](int s, int buf) {
        const size_t g0 = base + (size_t)s * S4 + w * 128 + lane;
        async_cp16(p4 + g0,      &sp[buf][w * 128]);
        async_cp16(p4 + g0 + 64, &sp[buf][w * 128 + 64]);
        async_cp16(q4 + g0,      &sq[buf][w * 128]);
        async_cp16(q4 + g0 + 64, &sq[buf][w * 128 + 64]);
    };

    stage(0, 0);
    float a0 = 0.0f, a1 = 0.0f, a2 = 0.0f, a3 = 0.0f;

    #pragma unroll
    for (int s = 0; s < STAGES; ++s) {
        const int buf = s & 1;
        // Barrier (with its implicit vmcnt drain) makes stage(s) visible and
        // guarantees every wave finished reading buf before it is re-staged.
        __syncthreads();
        if (s + 1 < STAGES) stage(s + 1, buf ^ 1);   // DMA overlaps compute(s)
        vfloat4 pv0 = sp[buf][t];
        vfloat4 qv0 = sq[buf][t];
        vfloat4 pv1 = sp[buf][t + 256];
        vfloat4 qv1 = sq[buf][t + 256];
        kl_acc4(pv0, qv0, a0, a1, a2, a3);
        kl_acc4(pv1, qv1, a0, a1, a2, a3);
    }

    float acc = (a0 + a1) + (a2 + a3);
    block_reduce_and_atomic(acc, out);
}

// Generic fallback: grid-stride, any N.
__global__ __launch_bounds__(BLOCK) void kl_div_generic(
        const float* __restrict__ p,
        const float* __restrict__ q,
        float* __restrict__ out,
        int n) {
    const int nvec = n >> 2;
    const vfloat4* __restrict__ p4 = reinterpret_cast<const vfloat4*>(p);
    const vfloat4* __restrict__ q4 = reinterpret_cast<const vfloat4*>(q);

    float acc = 0.0f;
    const int stride = gridDim.x * blockDim.x;
    for (int i = blockIdx.x * blockDim.x + threadIdx.x; i < nvec; i += stride) {
        vfloat4 pv = p4[i];
        vfloat4 qv = q4[i];
        kl_acc(pv.x, qv.x, acc);
        kl_acc(pv.y, qv.y, acc);
        kl_acc(pv.z, qv.z, acc);
        kl_acc(pv.w, qv.w, acc);
    }
    for (int i = (nvec << 2) + blockIdx.x * blockDim.x + threadIdx.x; i < n; i += stride) {
        kl_acc(p[i], q[i], acc);
    }
    block_reduce_and_atomic(acc, out);
}

extern "C" void kernel_launch(void* const* d_in, const int* in_sizes, int n_in,
                              void* d_out, int out_size, void* d_ws, size_t ws_size,
                              hipStream_t stream) {
    const float* p = (const float*)d_in[0];
    const float* q = (const float*)d_in[1];
    float* out = (float*)d_out;
    const int n = in_sizes[0];

    // d_out is re-poisoned to 0xAA before every timed launch — zero it.
    hipMemsetAsync(out, 0, sizeof(float), stream);

    if (n == GRID * S4 * STAGES * 4) {
        kl_div_lds<<<GRID, BLOCK, 0, stream>>>(
            reinterpret_cast<const vfloat4*>(p),
            reinterpret_cast<const vfloat4*>(q), out);
    } else {
        kl_div_generic<<<GRID, BLOCK, 0, stream>>>(p, q, out, n);
    }
}

// Round 6
// 267.619 us; speedup vs baseline: 1.0449x; 1.0449x over previous
//
#include <hip/hip_runtime.h>

#define BLOCK  256
#define GRID   2048
#define S4     512    // float4 per array per stage (8 KiB)
#define STAGES 8      // 2048 blocks * 512 * 8 * 4 elem = 2^25

typedef float vfloat4 __attribute__((ext_vector_type(4)));

// Async DMA global -> LDS, 16 B per lane; LDS dest is wave-uniform base.
__device__ __forceinline__ void async_cp16(const vfloat4* g, vfloat4* lds_base) {
    __builtin_amdgcn_global_load_lds(
        (const __attribute__((address_space(1))) unsigned int*)g,
        (__attribute__((address_space(3))) unsigned int*)lds_base,
        16, 0, 0);
}

__device__ __forceinline__ void kl_acc(float p, float q, float& acc) {
    // log2-space: acc += p*(log2 p - log2 q) + (1-p)*(log2(1-p) - log2(1-q))
    float omp = 1.0f - p;
    float omq = 1.0f - q;
    float d1  = __log2f(p)   - __log2f(q);
    float d2  = __log2f(omp) - __log2f(omq);
    acc = fmaf(p,   d1, acc);
    acc = fmaf(omp, d2, acc);
}

__device__ __forceinline__ void kl_acc4(vfloat4 pv, vfloat4 qv,
                                        float& a0, float& a1, float& a2, float& a3) {
    kl_acc(pv.x, qv.x, a0);
    kl_acc(pv.y, qv.y, a1);
    kl_acc(pv.z, qv.z, a2);
    kl_acc(pv.w, qv.w, a3);
}

__device__ __forceinline__ void block_reduce_and_atomic(float acc, float* out) {
    const float LN2 = 0.69314718055994530942f;
    #pragma unroll
    for (int off = 32; off > 0; off >>= 1)
        acc += __shfl_down(acc, off, 64);

    __shared__ float wave_sums[BLOCK / 64];
    const int lane = threadIdx.x & 63;
    const int wave = threadIdx.x >> 6;
    if (lane == 0) wave_sums[wave] = acc;
    __syncthreads();

    if (threadIdx.x == 0) {
        float s = 0.0f;
        #pragma unroll
        for (int w = 0; w < BLOCK / 64; ++w) s += wave_sums[w];
        atomicAdd(out, s * LN2);
    }
}

// Dual-path streamer: p via LDS-DMA queue, q via direct-to-VGPR NT loads.
// Tests whether the ~2.6 TB/s read clamp is per-path (outstanding-miss
// queue -> 2x possible) or a shared L2-miss fabric ceiling (-> no change).
__global__ __launch_bounds__(BLOCK, 4) void kl_div_dual(
        const vfloat4* __restrict__ p4,
        const vfloat4* __restrict__ q4,
        float* __restrict__ out) {
    __shared__ vfloat4 sp[2][S4];

    const int t    = threadIdx.x;
    const int w    = t >> 6;          // wave 0..3
    const int lane = t & 63;
    const size_t base = (size_t)blockIdx.x * (S4 * STAGES);  // float4 index

    // p: wave w DMA-stages its 128-float4 quarter (2 instrs).
    auto stage_p = [&](int s, int buf) {
        const size_t g0 = base + (size_t)s * S4 + w * 128 + lane;
        async_cp16(p4 + g0,      &sp[buf][w * 128]);
        async_cp16(p4 + g0 + 64, &sp[buf][w * 128 + 64]);
    };
    // q: 2 NT float4 per thread per stage, direct to VGPRs.
    auto load_q = [&](int s, vfloat4& qa, vfloat4& qb) {
        const size_t g0 = base + (size_t)s * S4 + t;
        qa = __builtin_nontemporal_load(q4 + g0);
        qb = __builtin_nontemporal_load(q4 + g0 + 256);
    };

    stage_p(0, 0);
    vfloat4 qa, qb;
    load_q(0, qa, qb);

    float a0 = 0.0f, a1 = 0.0f, a2 = 0.0f, a3 = 0.0f;

    #pragma unroll
    for (int s = 0; s < STAGES; ++s) {
        const int buf = s & 1;
        vfloat4 qan, qbn;
        if (s + 1 < STAGES) {
            stage_p(s + 1, buf ^ 1);     // DMA queue: next p stage
            load_q(s + 1, qan, qbn);     // VGPR queue: next q stage
        }
        // Keep the prefetches above this line; compute below uses stage s.
        __builtin_amdgcn_sched_barrier(0);
        __syncthreads();                 // drains vmem; sp[buf] now valid
        vfloat4 pv0 = sp[buf][t];
        vfloat4 pv1 = sp[buf][t + 256];
        kl_acc4(pv0, qa, a0, a1, a2, a3);
        kl_acc4(pv1, qb, a0, a1, a2, a3);
        qa = qan; qb = qbn;
    }

    float acc = (a0 + a1) + (a2 + a3);
    block_reduce_and_atomic(acc, out);
}

// Generic fallback: grid-stride, any N.
__global__ __launch_bounds__(BLOCK) void kl_div_generic(
        const float* __restrict__ p,
        const float* __restrict__ q,
        float* __restrict__ out,
        int n) {
    const int nvec = n >> 2;
    const vfloat4* __restrict__ p4 = reinterpret_cast<const vfloat4*>(p);
    const vfloat4* __restrict__ q4 = reinterpret_cast<const vfloat4*>(q);

    float acc = 0.0f;
    const int stride = gridDim.x * blockDim.x;
    for (int i = blockIdx.x * blockDim.x + threadIdx.x; i < nvec; i += stride) {
        vfloat4 pv = p4[i];
        vfloat4 qv = q4[i];
        kl_acc(pv.x, qv.x, acc);
        kl_acc(pv.y, qv.y, acc);
        kl_acc(pv.z, qv.z, acc);
        kl_acc(pv.w, qv.w, acc);
    }
    for (int i = (nvec << 2) + blockIdx.x * blockDim.x + threadIdx.x; i < n; i += stride) {
        kl_acc(p[i], q[i], acc);
    }
    block_reduce_and_atomic(acc, out);
}

extern "C" void kernel_launch(void* const* d_in, const int* in_sizes, int n_in,
                              void* d_out, int out_size, void* d_ws, size_t ws_size,
                              hipStream_t stream) {
    const float* p = (const float*)d_in[0];
    const float* q = (const float*)d_in[1];
    float* out = (float*)d_out;
    const int n = in_sizes[0];

    // d_out is re-poisoned to 0xAA before every timed launch — zero it.
    hipMemsetAsync(out, 0, sizeof(float), stream);

    if (n == GRID * S4 * STAGES * 4) {
        kl_div_dual<<<GRID, BLOCK, 0, stream>>>(
            reinterpret_cast<const vfloat4*>(p),
            reinterpret_cast<const vfloat4*>(q), out);
    } else {
        kl_div_generic<<<GRID, BLOCK, 0, stream>>>(p, q, out, n);
    }
}

// Round 7
// 267.095 us; speedup vs baseline: 1.0469x; 1.0020x over previous
//
#include <hip/hip_runtime.h>

#define BLOCK  256
#define GRID   2048
#define W4     1024   // float4 per wave
#define S4W    128    // float4 per wave per stage (2 KiB)
#define STAGES 8
#define RING   4      // per-wave LDS ring slots

typedef float vfloat4 __attribute__((ext_vector_type(4)));

// Async DMA global -> LDS, 16 B/lane; LDS dest is wave-uniform base, HW
// scatters lane i to base + i*16.
__device__ __forceinline__ void async_cp16(const vfloat4* g, vfloat4* lds_base) {
    __builtin_amdgcn_global_load_lds(
        (const __attribute__((address_space(1))) unsigned int*)g,
        (__attribute__((address_space(3))) unsigned int*)lds_base,
        16, 0, 0);
}

__device__ __forceinline__ void kl_acc(float p, float q, float& acc) {
    // log2-space: acc += p*(log2 p - log2 q) + (1-p)*(log2(1-p) - log2(1-q))
    float omp = 1.0f - p;
    float omq = 1.0f - q;
    float d1  = __log2f(p)   - __log2f(q);
    float d2  = __log2f(omp) - __log2f(omq);
    acc = fmaf(p,   d1, acc);
    acc = fmaf(omp, d2, acc);
}

__device__ __forceinline__ void kl_acc4(vfloat4 pv, vfloat4 qv,
                                        float& a0, float& a1, float& a2, float& a3) {
    kl_acc(pv.x, qv.x, a0);
    kl_acc(pv.y, qv.y, a1);
    kl_acc(pv.z, qv.z, a2);
    kl_acc(pv.w, qv.w, a3);
}

__device__ __forceinline__ void block_reduce_and_atomic(float acc, float* out) {
    const float LN2 = 0.69314718055994530942f;
    #pragma unroll
    for (int off = 32; off > 0; off >>= 1)
        acc += __shfl_down(acc, off, 64);

    __shared__ float wave_sums[BLOCK / 64];
    const int lane = threadIdx.x & 63;
    const int wave = threadIdx.x >> 6;
    if (lane == 0) wave_sums[wave] = acc;
    __syncthreads();

    if (threadIdx.x == 0) {
        float s = 0.0f;
        #pragma unroll
        for (int w = 0; w < BLOCK / 64; ++w) s += wave_sums[w];
        atomicAdd(out, s * LN2);
    }
}

// Per-wave autonomous ring streamer: no block barriers in the main loop.
// Each wave keeps 3 stages (12 vmem ops, ~12 KB) permanently in flight on
// BOTH queues (p via LDS-DMA, q via NT->VGPR); stage completion is awaited
// with s_waitcnt vmcnt(12/8/4/0) — the queue never drains to zero except at
// the end (hipBLASLt discipline).
__global__ __launch_bounds__(BLOCK, 4) void kl_div_ring(
        const vfloat4* __restrict__ p4,
        const vfloat4* __restrict__ q4,
        float* __restrict__ out) {
    __shared__ vfloat4 sp[4][RING][S4W];   // 4 waves x 4 slots x 2 KiB = 32 KiB

    const int t    = threadIdx.x;
    const int w    = t >> 6;
    const int lane = t & 63;
    const size_t wbase = ((size_t)blockIdx.x * 4 + w) * W4;

    vfloat4 qr[RING][2];
    float a0 = 0.0f, a1 = 0.0f, a2 = 0.0f, a3 = 0.0f;

    // Issue stage S into ring slot S&3: 2 p-DMA + 2 q-NT = 4 vmem ops.
    #define ISSUE(S) do {                                                  \
        const size_t g0 = wbase + (size_t)(S) * S4W + lane;                \
        vfloat4* dst = &sp[w][(S) & (RING - 1)][0];                        \
        async_cp16(p4 + g0,      dst);                                     \
        async_cp16(p4 + g0 + 64, dst + 64);                                \
        qr[(S) & (RING - 1)][0] = __builtin_nontemporal_load(q4 + g0);     \
        qr[(S) & (RING - 1)][1] = __builtin_nontemporal_load(q4 + g0 + 64);\
    } while (0)

    // Consume stage S; VM = vmem ops allowed to remain outstanding
    // (= 4 * stages-still-ahead). Memory clobber + sched_barrier pin the
    // DMA -> waitcnt -> ds_read order against both mid-end and scheduler.
    #define STEP(S, VM) do {                                               \
        if ((S) + 3 < STAGES) ISSUE((S) + 3);                              \
        __builtin_amdgcn_sched_barrier(0);                                 \
        __builtin_amdgcn_s_waitcnt((VM) | 0x70 | 0xF00);                   \
        asm volatile("" ::: "memory");                                     \
        __builtin_amdgcn_sched_barrier(0);                                 \
        vfloat4 pv0 = sp[w][(S) & (RING - 1)][lane];                       \
        vfloat4 pv1 = sp[w][(S) & (RING - 1)][lane + 64];                  \
        kl_acc4(pv0, qr[(S) & (RING - 1)][0], a0, a1, a2, a3);             \
        kl_acc4(pv1, qr[(S) & (RING - 1)][1], a0, a1, a2, a3);             \
    } while (0)

    ISSUE(0); ISSUE(1); ISSUE(2);
    STEP(0, 12); STEP(1, 12); STEP(2, 12); STEP(3, 12);
    STEP(4, 12); STEP(5, 8);  STEP(6, 4);  STEP(7, 0);

    #undef STEP
    #undef ISSUE

    float acc = (a0 + a1) + (a2 + a3);
    block_reduce_and_atomic(acc, out);
}

// Generic fallback: grid-stride, any N.
__global__ __launch_bounds__(BLOCK) void kl_div_generic(
        const float* __restrict__ p,
        const float* __restrict__ q,
        float* __restrict__ out,
        int n) {
    const int nvec = n >> 2;
    const vfloat4* __restrict__ p4 = reinterpret_cast<const vfloat4*>(p);
    const vfloat4* __restrict__ q4 = reinterpret_cast<const vfloat4*>(q);

    float acc = 0.0f;
    const int stride = gridDim.x * blockDim.x;
    for (int i = blockIdx.x * blockDim.x + threadIdx.x; i < nvec; i += stride) {
        vfloat4 pv = p4[i];
        vfloat4 qv = q4[i];
        kl_acc(pv.x, qv.x, acc);
        kl_acc(pv.y, qv.y, acc);
        kl_acc(pv.z, qv.z, acc);
        kl_acc(pv.w, qv.w, acc);
    }
    for (int i = (nvec << 2) + blockIdx.x * blockDim.x + threadIdx.x; i < n; i += stride) {
        kl_acc(p[i], q[i], acc);
    }
    block_reduce_and_atomic(acc, out);
}

extern "C" void kernel_launch(void* const* d_in, const int* in_sizes, int n_in,
                              void* d_out, int out_size, void* d_ws, size_t ws_size,
                              hipStream_t stream) {
    const float* p = (const float*)d_in[0];
    const float* q = (const float*)d_in[1];
    float* out = (float*)d_out;
    const int n = in_sizes[0];

    // d_out is re-poisoned to 0xAA before every timed launch — zero it.
    hipMemsetAsync(out, 0, sizeof(float), stream);

    if (n == GRID * 4 * W4 * 4) {   // 2048 blocks * 4 waves * 1024 float4 * 4
        kl_div_ring<<<GRID, BLOCK, 0, stream>>>(
            reinterpret_cast<const vfloat4*>(p),
            reinterpret_cast<const vfloat4*>(q), out);
    } else {
        kl_div_generic<<<GRID, BLOCK, 0, stream>>>(p, q, out, n);
    }
}